// Round 7
// baseline (123.129 us; speedup 1.0000x reference)
//
#include <hip/hip_runtime.h>
#include <hip/hip_bf16.h>
#include <math.h>

// Chamfer distance, fully fused single kernel, B=8, N=M=8192, D=3, fp32.
//   C[m][n] = q_m.r_n - 0.5*||r_n||^2 via ONE v_mfma_f32_32x32x16_bf16:
//     lanes<32  (k0-7) : A={qh,1, ql,0}  B={rh,wh, rh,wh}
//     lanes>=32 (k8-15): A={qh,1, 0,0}   B={rl,wl, 0,0}
//   (hi/lo bf16 split; dropped ql.rl term ~2^-17 relative)
//   min_j d2 = ||q||^2_fp32 - 2*max_n C, clamped at 0.
// R13: six different nn bodies all gave total ~98-100us. Decomposition of
// the timed window: 43us = 256MiB WS POISON-FILL (harness re-poisons d_ws
// every iteration because we use it) + prep + nn + reduce + gaps. The nn
// body is exonerated; the workspace is the target. This version uses NO
// workspace at all:
//   - no prep: B-fragments packed on the fly from raw floats (~30 VALU/pt;
//     VALU floor ~16us ~= MFMA floor 13.8us; data is 1.5MB = L2-resident)
//   - NCHUNK=1: each block owns its 256 queries end-to-end -> no kpart,
//     no reduce kernel; block sum + one atomicAdd (harness memsets out)
//   - grid 32x16 = 512 blocks = exactly 2/CU, no tail; zero main-loop
//     barriers; 1-iter raw prefetch; per-wave quarter rotation de-convoys L2
//   - intrinsic MFMA (hazard recognizer active; verified absmax 0.0 path)
// Discriminator: poison conditional on ws use -> total ~30-45us; poison
// unconditional -> total ~72-85us (still -10us, and the fused kernel
// finally appears in the counters).

#define BLOCK 256
#define WAVES 4
#define QPW 64        // queries per wave (two 32-row MFMA groups)

typedef short short8 __attribute__((ext_vector_type(8)));
typedef float f32x16 __attribute__((ext_vector_type(16)));

__device__ __forceinline__ unsigned int bf16hi(float f) {
    __hip_bfloat16 h = __float2bfloat16(f);
    return (unsigned int)*reinterpret_cast<unsigned short*>(&h);
}
__device__ __forceinline__ float bf16f(unsigned int u) {
    unsigned int v = u << 16;
    return *reinterpret_cast<float*>(&v);
}
__device__ __forceinline__ void cvt_split(float v, unsigned int& hi, unsigned int& lo) {
    hi = bf16hi(v);
    lo = bf16hi(v - bf16f(hi));
}

#define MFMA(a, b, c) __builtin_amdgcn_mfma_f32_32x32x16_bf16((a), (b), (c), 0, 0, 0)

union U4S { uint4 v; short8 s; };

// Pack one ref point into its 4 fragment words (hi pair, lo pair).
__device__ __forceinline__ void pack_ref(float x, float y, float z,
                                         unsigned int& hx, unsigned int& hz,
                                         unsigned int& lx, unsigned int& lz) {
    const float n2 = x * x + y * y + z * z;
    const float w = -0.5f * n2;
    unsigned int xh, xl, yh, yl, zh, zl, wh, wl;
    cvt_split(x, xh, xl);
    cvt_split(y, yh, yl);
    cvt_split(z, zh, zl);
    cvt_split(w, wh, wl);
    hx = xh | (yh << 16); hz = zh | (wh << 16);
    lx = xl | (yl << 16); lz = zl | (wl << 16);
}

__global__ void __launch_bounds__(BLOCK, 2)
chamfer_kernel(const float* __restrict__ gts, const float* __restrict__ preds,
               int N, int M, int B, float invx, float invy,
               float* __restrict__ out) {
    const int z = blockIdx.y;
    const bool dirX = (z < B);
    const int b = dirX ? z : z - B;
    const int NQ = dirX ? N : M;
    const int NR = dirX ? M : N;
    const float* Q = (dirX ? gts : preds) + (size_t)b * NQ * 3;
    const float* R = (dirX ? preds : gts) + (size_t)b * NR * 3;
    const float inv = dirX ? invx : invy;

    const int tid = threadIdx.x;
    const int lane = tid & 63;
    const int wave = tid >> 6;
    const int m = lane & 31;
    const bool isHi = lane < 32;                    // supplies k=0..7 (hi parts)
    const unsigned int loMask = isHi ? 0xFFFFFFFFu : 0u;
    const int qBase = (blockIdx.x * WAVES + wave) * QPW;

    // ---- A fragments from raw queries (two 32-row groups); keep n2 exact.
    float n2q0, n2q1;
    short8 A0, A1;
    {
        const float* qp = Q + 3 * (size_t)(qBase + m);
        const float x = qp[0], y = qp[1], zz = qp[2];
        n2q0 = x * x + y * y + zz * zz;
        unsigned int xh, xl, yh, yl, zh, zl;
        cvt_split(x, xh, xl); cvt_split(y, yh, yl); cvt_split(zz, zh, zl);
        U4S a;
        a.v.x = xh | (yh << 16);
        a.v.y = zh | 0x3F800000u;                   // (qzh, 1.0bf16)
        a.v.z = (xl | (yl << 16)) & loMask;
        a.v.w = zl & loMask;
        A0 = a.s;
    }
    {
        const float* qp = Q + 3 * (size_t)(qBase + 32 + m);
        const float x = qp[0], y = qp[1], zz = qp[2];
        n2q1 = x * x + y * y + zz * zz;
        unsigned int xh, xl, yh, yl, zh, zl;
        cvt_split(x, xh, xl); cvt_split(y, yh, yl); cvt_split(zz, zh, zl);
        U4S a;
        a.v.x = xh | (yh << 16);
        a.v.y = zh | 0x3F800000u;
        a.v.z = (xl | (yl << 16)) & loMask;
        a.v.w = zl & loMask;
        A1 = a.s;
    }

    f32x16 k0, k1, zc;
    #pragma unroll
    for (int r = 0; r < 16; ++r) { k0[r] = -INFINITY; k1[r] = -INFINITY; zc[r] = 0.0f; }

    // Ref stream: tile t = points [32t, 32t+32); this lane's point is
    // t*32 + m (both lane-halves read the same point; hi half consumes hi
    // parts, lo half the residuals). All data L2-resident (96 KB/cloud).
    const int NT = NR / 32;                         // 256 tiles (pow2)
    const int rot = ((wave + blockIdx.x) & 3) * (NT / 4);   // de-convoy start

    float x0, y0, z0, x1, y1, z1;                   // current 2 tiles (raw)
    {
        const float* p0 = R + 3 * (size_t)(rot * 32 + m);
        const float* p1 = p0 + 96;                  // next tile (+32 pts)
        x0 = p0[0]; y0 = p0[1]; z0 = p0[2];
        x1 = p1[0]; y1 = p1[1]; z1 = p1[2];
    }

    #pragma unroll 1
    for (int i = 0; i < NT / 2; ++i) {
        // prefetch next iteration's raw points (1 iter ~ pack+mfma+fold
        // latency; wrap at the end loads valid-but-unused data)
        const int tn = (2 * (i + 1) + rot) & (NT - 1);
        const float* p0 = R + 3 * (size_t)(tn * 32 + m);
        const float nx0 = p0[0], ny0 = p0[1], nz0 = p0[2];
        const float nx1 = p0[96], ny1 = p0[97], nz1 = p0[98];

        // pack current 2 tiles into B fragments
        unsigned int hx0, hz0, lx0, lz0, hx1, hz1, lx1, lz1;
        pack_ref(x0, y0, z0, hx0, hz0, lx0, lz0);
        pack_ref(x1, y1, z1, hx1, hz1, lx1, lz1);
        U4S b0, b1;
        b0.v.x = isHi ? hx0 : lx0;
        b0.v.y = isHi ? hz0 : lz0;
        b0.v.z = hx0 & loMask;
        b0.v.w = hz0 & loMask;
        b1.v.x = isHi ? hx1 : lx1;
        b1.v.y = isHi ? hz1 : lz1;
        b1.v.z = hx1 & loMask;
        b1.v.w = hz1 & loMask;

        const f32x16 c0 = MFMA(A0, b0.s, zc);
        const f32x16 c1 = MFMA(A0, b1.s, zc);
        const f32x16 c2 = MFMA(A1, b0.s, zc);
        const f32x16 c3 = MFMA(A1, b1.s, zc);
        #pragma unroll
        for (int r = 0; r < 16; ++r)
            k0[r] = fmaxf(fmaxf(c0[r], c1[r]), k0[r]);   // v_max3
        #pragma unroll
        for (int r = 0; r < 16; ++r)
            k1[r] = fmaxf(fmaxf(c2[r], c3[r]), k1[r]);

        x0 = nx0; y0 = ny0; z0 = nz0;
        x1 = nx1; y1 = ny1; z1 = nz1;
    }

    // ---- epilogue: LDS transpose (wave-private, no barrier), then each
    // lane max-reduces one query row.
    // C/D layout: col=lane&31, row=(r&3)+8*(r>>2)+4*(lane>>5).
    __shared__ float sT[WAVES][64][36];             // +4 pad: conflict-free
    #pragma unroll
    for (int r = 0; r < 16; ++r) {
        const int row = (r & 3) + 8 * (r >> 2) + 4 * (lane >> 5);
        sT[wave][row][m]      = k0[r];              // group 0 -> rows 0..31
        sT[wave][32 + row][m] = k1[r];              // group 1 -> rows 32..63
    }
    // compiler inserts the lgkmcnt waits.
    const float4* rowp = (const float4*)&sT[wave][lane][0];
    float4 m01 = rowp[0];
    #pragma unroll
    for (int kk = 1; kk < 8; ++kk) {
        const float4 t = rowp[kk];
        m01.x = fmaxf(m01.x, t.x); m01.y = fmaxf(m01.y, t.y);
        m01.z = fmaxf(m01.z, t.z); m01.w = fmaxf(m01.w, t.w);
    }
    const float cmax = fmaxf(fmaxf(m01.x, m01.y), fmaxf(m01.z, m01.w));

    // lane reduces row `lane` = query qBase+lane; its exact fp32 norm:
    const float q2own = isHi ? n2q0 : n2q1;
    float v = fmaxf(q2own - 2.0f * cmax, 0.0f) * inv;

    // block reduction -> one atomicAdd (out zeroed by harness each iter)
    #pragma unroll
    for (int off = 32; off; off >>= 1) v += __shfl_xor(v, off);
    __shared__ float waveSums[WAVES];
    if (lane == 0) waveSums[wave] = v;
    __syncthreads();
    if (tid == 0) {
        float s = 0.0f;
        #pragma unroll
        for (int w = 0; w < WAVES; ++w) s += waveSums[w];
        atomicAdd(out, s);
    }
}

extern "C" void kernel_launch(void* const* d_in, const int* in_sizes, int n_in,
                              void* d_out, int out_size, void* d_ws, size_t ws_size,
                              hipStream_t stream) {
    const float* gts   = (const float*)d_in[0];   // [B, N, 3]
    const float* preds = (const float*)d_in[1];   // [B, M, 3]
    float* out = (float*)d_out;

    const int B = 8;
    const int N = in_sizes[0] / (B * 3);
    const int M = in_sizes[1] / (B * 3);
    const int nG = B * N, nP = B * M;

    // NO workspace use: d_ws untouched (target: skip the 256MiB poison fill).
    dim3 grid(N / (WAVES * QPW), 2 * B);          // 32 x 16 = 512 = 2/CU
    chamfer_kernel<<<grid, BLOCK, 0, stream>>>(
        gts, preds, N, M, B, 1.0f / (float)nG, 1.0f / (float)nP, out);
}

// Round 8
// 96.546 us; speedup vs baseline: 1.2753x; 1.2753x over previous
//
#include <hip/hip_runtime.h>
#include <hip/hip_bf16.h>
#include <math.h>

// Chamfer distance, B=8, N=M=8192, D=3, fp32.
//   C[m][n] = q_m.r_n - 0.5*||r_n||^2 via ONE v_mfma_f32_32x32x16_bf16:
//     lanes<32  (k0-7) : A={qh,1, ql,0}  B={rh,wh, rh,wh}
//     lanes>=32 (k8-15): A={qh,1, 0,0}   B={rl,wl, 0,0}
//   min_j d2 = ||q||^2_fp32 - 2*max_n C, clamped at 0.
// R14: counter-calibrated model. Per-SIMD: one 32x32x16 MFMA = 32 cyc
// (m119's 8.07 is per-CU over 4 SIMDs); MFMA and VALU SERIALIZE on issue
// within a SIMD (R0: 258+356=614 of 780 ✓; R7: 256+800 of 1534 ✓). Every
// 42us variant carried ~90 VALU/iter. R7 also proved the 256MiB ws poison
// fill runs UNCONDITIONALLY (123 = 81.8 + 41.3 with ws untouched) -> ws is
// free, prep-side packing is back. This version minimizes VALU per MFMA:
//   - prep pre-expands per-lane B-fragments into recB (4MB ws, ~2us)
//   - inner loop: 2 coalesced uint4 loads (SGPR-base + imm-offset, ~1 VALU
//     of addr math per iter), 4 MFMA, 32 v_max3, bit_cast (no union moves)
//     => ~35 VALU/iter vs ~90 before; window ~2x(129+70)=400 cyc
//   - fused epilogue: NCHUNK=1, block sum + atomicAdd (no kpart/reduce);
//     A-frags packed from raw Q in prologue (once, negligible)
//   - straight stream, no rotation: convoying waves share L1 lines
// Predicted: nn 20-24us (MfmaUtil 55-65, VALUBusy 30-38), total ~68-74.
// Pre-commit: if ~40us w/ MfmaUtil~33 -> issue/latency stall -> next raises
// occupancy (QPW=32, 4 waves/SIMD).

#define BLOCK 256
#define WAVES 4
#define QPW 64        // queries per wave (two 32-row MFMA groups)

typedef short short8 __attribute__((ext_vector_type(8)));
typedef float f32x16 __attribute__((ext_vector_type(16)));

__device__ __forceinline__ unsigned int bf16hi(float f) {
    __hip_bfloat16 h = __float2bfloat16(f);
    return (unsigned int)*reinterpret_cast<unsigned short*>(&h);
}
__device__ __forceinline__ float bf16f(unsigned int u) {
    unsigned int v = u << 16;
    return *reinterpret_cast<float*>(&v);
}
__device__ __forceinline__ void cvt_split(float v, unsigned int& hi, unsigned int& lo) {
    hi = bf16hi(v);
    lo = bf16hi(v - bf16f(hi));
}

#define MFMA(a, b, c) __builtin_amdgcn_mfma_f32_32x32x16_bf16((a), (b), (c), 0, 0, 0)

// recB: pre-expanded B-fragment stream, tile t = points [32t,32t+32),
// 1024B per tile:
//   bytes [t*1024 + m*16]       = {hx,hz, hx,hz}  (hi dup, consumed by lanes<32)
//   bytes [t*1024 + 512 + m*16] = {lx,lz, 0, 0}   (lo,     consumed by lanes>=32)
// where hx = xh|(yh<<16), hz = zh|(wh<<16), w = -0.5*||p||^2.
__global__ void prep_kernel(const float* __restrict__ gts, const float* __restrict__ preds,
                            int nG, int nP, unsigned char* __restrict__ recB) {
    const int idx = blockIdx.x * blockDim.x + threadIdx.x;
    if (idx >= nG + nP) return;
    const float* src;
    unsigned char* rb;
    if (idx < nG) {
        src = gts + 3 * (size_t)idx;
        rb  = recB + (size_t)(idx >> 5) * 1024 + (size_t)(idx & 31) * 16;
    } else {
        const int j = idx - nG;
        src = preds + 3 * (size_t)j;
        rb  = recB + (size_t)nG * 32 + (size_t)(j >> 5) * 1024 + (size_t)(j & 31) * 16;
    }
    const float x = src[0], y = src[1], z = src[2];
    const float w = -0.5f * (x * x + y * y + z * z);
    unsigned int xh, xl, yh, yl, zh, zl, wh, wl;
    cvt_split(x, xh, xl); cvt_split(y, yh, yl);
    cvt_split(z, zh, zl); cvt_split(w, wh, wl);
    const unsigned int hx = xh | (yh << 16), hz = zh | (wh << 16);
    const unsigned int lx = xl | (yl << 16), lz = zl | (wl << 16);
    *(uint4*)(rb)       = make_uint4(hx, hz, hx, hz);
    *(uint4*)(rb + 512) = make_uint4(lx, lz, 0u, 0u);
}

__global__ void __launch_bounds__(BLOCK, 2)
chamfer_kernel(const float* __restrict__ gts, const float* __restrict__ preds,
               const uint4* __restrict__ recB, int N, int M, int B,
               float invx, float invy, float* __restrict__ out) {
    const int z = blockIdx.y;
    const bool dirX = (z < B);
    const int b = dirX ? z : z - B;
    const int NQ = dirX ? N : M;
    const int NR = dirX ? M : N;
    const float* Q = (dirX ? gts : preds) + (size_t)b * NQ * 3;
    const float inv = dirX ? invx : invy;
    // this direction's ref fragments (2 uint4 per point)
    const uint4* Rb4 = recB + (dirX ? (size_t)B * N * 2 : 0) + (size_t)b * NR * 2;

    const int tid = threadIdx.x;
    const int lane = tid & 63;
    const int wave = tid >> 6;
    const int m = lane & 31;
    const bool isHi = lane < 32;
    const unsigned int loMask = isHi ? 0xFFFFFFFFu : 0u;
    const int qBase = (blockIdx.x * WAVES + wave) * QPW;

    // ---- A fragments from raw queries (once; ~100 VALU, negligible)
    float n2q0, n2q1;
    short8 A0, A1;
    {
        const float* qp = Q + 3 * (size_t)(qBase + m);
        const float x = qp[0], y = qp[1], zz = qp[2];
        n2q0 = x * x + y * y + zz * zz;
        unsigned int xh, xl, yh, yl, zh, zl;
        cvt_split(x, xh, xl); cvt_split(y, yh, yl); cvt_split(zz, zh, zl);
        uint4 a = make_uint4(xh | (yh << 16), zh | 0x3F800000u,
                             (xl | (yl << 16)) & loMask, zl & loMask);
        A0 = __builtin_bit_cast(short8, a);
    }
    {
        const float* qp = Q + 3 * (size_t)(qBase + 32 + m);
        const float x = qp[0], y = qp[1], zz = qp[2];
        n2q1 = x * x + y * y + zz * zz;
        unsigned int xh, xl, yh, yl, zh, zl;
        cvt_split(x, xh, xl); cvt_split(y, yh, yl); cvt_split(zz, zh, zl);
        uint4 a = make_uint4(xh | (yh << 16), zh | 0x3F800000u,
                             (xl | (yl << 16)) & loMask, zl & loMask);
        A1 = __builtin_bit_cast(short8, a);
    }

    f32x16 k0, k1, zc;
    #pragma unroll
    for (int r = 0; r < 16; ++r) { k0[r] = -INFINITY; k1[r] = -INFINITY; zc[r] = 0.0f; }

    // Lane l reads its 16B fragment of tile t at Rb4[t*64 + lane].
    // Ping-pong 4-tile groups (= 2 iterations, ~400 cyc) ahead of use.
    // Loads use a slowly-advancing base + imm offsets {0,64,128,192} so the
    // compiler emits global_load_dwordx4 saddr/imm forms: ~1 VALU/iter.
#define DO2(ba, bb) do {                                                     \
        const short8 sa_ = __builtin_bit_cast(short8, (ba));                 \
        const short8 sb_ = __builtin_bit_cast(short8, (bb));                 \
        const f32x16 c0_ = MFMA(A0, sa_, zc);                                \
        const f32x16 c1_ = MFMA(A0, sb_, zc);                                \
        const f32x16 c2_ = MFMA(A1, sa_, zc);                                \
        const f32x16 c3_ = MFMA(A1, sb_, zc);                                \
        _Pragma("unroll")                                                    \
        for (int r = 0; r < 16; ++r)                                         \
            k0[r] = fmaxf(fmaxf(c0_[r], c1_[r]), k0[r]);                     \
        _Pragma("unroll")                                                    \
        for (int r = 0; r < 16; ++r)                                         \
            k1[r] = fmaxf(fmaxf(c2_[r], c3_[r]), k1[r]);                     \
    } while (0)

    const int NT = NR / 32;                         // 256 tiles
    const uint4* p = Rb4 + lane;
    uint4 S0 = p[0], S1 = p[64], S2 = p[128], S3 = p[192];
    #pragma unroll 1
    for (int g = 0; g < NT / 4; g += 2) {
        const uint4* pT = p + 256;
        const uint4 T0 = pT[0], T1 = pT[64], T2 = pT[128], T3 = pT[192];
        DO2(S0, S1); DO2(S2, S3);
        const uint4* pS = p + 512;                  // last group: reads 4KB past
        S0 = pS[0]; S1 = pS[64]; S2 = pS[128]; S3 = pS[192];   // chunk (ws interior
        DO2(T0, T1); DO2(T2, T3);                   // or scratch) - unused
        p += 512;
    }
#undef DO2

    // ---- epilogue: LDS transpose (wave-private, no barrier), then each
    // lane max-reduces one query row.
    // C/D layout: col=lane&31, row=(r&3)+8*(r>>2)+4*(lane>>5).
    __shared__ float sT[WAVES][64][36];             // +4 pad: conflict-free
    #pragma unroll
    for (int r = 0; r < 16; ++r) {
        const int row = (r & 3) + 8 * (r >> 2) + 4 * (lane >> 5);
        sT[wave][row][m]      = k0[r];              // group 0 -> rows 0..31
        sT[wave][32 + row][m] = k1[r];              // group 1 -> rows 32..63
    }
    const float4* rowp = (const float4*)&sT[wave][lane][0];
    float4 m01 = rowp[0];
    #pragma unroll
    for (int kk = 1; kk < 8; ++kk) {
        const float4 t = rowp[kk];
        m01.x = fmaxf(m01.x, t.x); m01.y = fmaxf(m01.y, t.y);
        m01.z = fmaxf(m01.z, t.z); m01.w = fmaxf(m01.w, t.w);
    }
    const float cmax = fmaxf(fmaxf(m01.x, m01.y), fmaxf(m01.z, m01.w));

    // lane owns query qBase+lane; its exact fp32 norm from the prologue.
    const float q2own = isHi ? n2q0 : n2q1;
    float v = fmaxf(q2own - 2.0f * cmax, 0.0f) * inv;

    // block reduction -> one atomicAdd (out zeroed by harness each iter)
    #pragma unroll
    for (int off = 32; off; off >>= 1) v += __shfl_xor(v, off);
    __shared__ float waveSums[WAVES];
    if (lane == 0) waveSums[wave] = v;
    __syncthreads();
    if (tid == 0) {
        float s = 0.0f;
        #pragma unroll
        for (int w = 0; w < WAVES; ++w) s += waveSums[w];
        atomicAdd(out, s);
    }
}

extern "C" void kernel_launch(void* const* d_in, const int* in_sizes, int n_in,
                              void* d_out, int out_size, void* d_ws, size_t ws_size,
                              hipStream_t stream) {
    const float* gts   = (const float*)d_in[0];   // [B, N, 3]
    const float* preds = (const float*)d_in[1];   // [B, M, 3]
    float* out = (float*)d_out;

    const int B = 8;
    const int N = in_sizes[0] / (B * 3);
    const int M = in_sizes[1] / (B * 3);
    const int nG = B * N, nP = B * M;

    unsigned char* recB = (unsigned char*)d_ws;   // (nG+nP)*32B = 4 MB

    prep_kernel<<<(nG + nP + BLOCK - 1) / BLOCK, BLOCK, 0, stream>>>(
        gts, preds, nG, nP, recB);

    dim3 grid(N / (WAVES * QPW), 2 * B);          // 32 x 16 = 512 = 2/CU
    chamfer_kernel<<<grid, BLOCK, 0, stream>>>(
        gts, preds, (const uint4*)recB, N, M, B,
        1.0f / (float)nG, 1.0f / (float)nP, out);
}